// Round 1
// baseline (357.323 us; speedup 1.0000x reference)
//
#include <hip/hip_runtime.h>
#include <hip/hip_bf16.h>

// Edges GNN message MLP: per-edge RBF(100) + gather h[src],h[dst] (64+64)
// -> Linear(228->128) -> SiLU -> Linear(128->64).
// R3 design: barrier-free. Each wave owns WEDGES=32 edges end-to-end.
// R4 (this round): (a) h pre-converted to a bf16 table in workspace so each
// A-fragment gather is a single aligned 16B load (no f32->bf16 cvt chain,
// half the gather bytes); (b) SiLU uses v_rcp_f32 instead of the
// full-precision fdiv expansion (~10 VALU -> ~2 VALU per value).

#define FEAT     64
#define NMU      100
#define K1_REAL  228
#define HID      128
#define ODIM     64
#define K2       128
#define WEDGES   32        // edges per wave
#define BEDGES   128       // 4 waves/block
#define LDH2     136       // bf16 leading dim of per-wave H tile (16B-aligned rows)
#define HN8      400000    // (50000*64)/8 bf16x8 groups in h

typedef __bf16 bf16x8 __attribute__((ext_vector_type(8)));
typedef float  fx4    __attribute__((ext_vector_type(4)));

// Pack W1 [128 x 228] and W2 [64 x 128] fp32 -> bf16 MFMA B-fragment order.
// B1[((kk*4+q)*128 + n)*8 + j] = W1[n][kk*32 + q*8 + j]  (0 if k >= 228)
// B2[((kk*4+q)*64  + n)*8 + j] = W2[n][kk*32 + q*8 + j]
__global__ void pack_w(const float* __restrict__ W1, const float* __restrict__ W2,
                       __bf16* __restrict__ B1, __bf16* __restrict__ B2) {
    int i = blockIdx.x * 256 + threadIdx.x;     // 0..40959
    if (i < 32768) {
        int j  = i & 7;
        int n  = (i >> 3) & 127;
        int qk = i >> 10;
        int k  = (qk >> 2) * 32 + (qk & 3) * 8 + j;
        float v = (k < K1_REAL) ? W1[n * K1_REAL + k] : 0.0f;
        B1[i] = (__bf16)v;
    } else {
        int t = i - 32768;
        int j  = t & 7;
        int n  = (t >> 3) & 63;
        int qk = t >> 9;
        int k  = (qk >> 2) * 32 + (qk & 3) * 8 + j;
        B2[t] = (__bf16)W2[n * K2 + k];
    }
}

// Convert h [50000 x 64] fp32 -> bf16 table (row-major, same layout).
__global__ void pack_h(const float* __restrict__ h, __bf16* __restrict__ hb) {
    int i = blockIdx.x * 256 + threadIdx.x;     // one bf16x8 group each
    if (i >= HN8) return;
    const float4* p = (const float4*)h + (size_t)i * 2;
    float4 v0 = p[0];
    float4 v1 = p[1];
    bf16x8 b = { (__bf16)v0.x, (__bf16)v0.y, (__bf16)v0.z, (__bf16)v0.w,
                 (__bf16)v1.x, (__bf16)v1.y, (__bf16)v1.z, (__bf16)v1.w };
    ((bf16x8*)hb)[i] = b;
}

__device__ __forceinline__ bf16x8 hfrag_f32(const float* __restrict__ h, int node, int cb) {
    const float4* p = (const float4*)(h + (size_t)node * FEAT + cb);
    float4 v0 = p[0];
    float4 v1 = p[1];
    bf16x8 a = { (__bf16)v0.x, (__bf16)v0.y, (__bf16)v0.z, (__bf16)v0.w,
                 (__bf16)v1.x, (__bf16)v1.y, (__bf16)v1.z, (__bf16)v1.w };
    return a;
}

template<bool HB16>
__global__ __launch_bounds__(256, 4)
void edges_fused(const float* __restrict__ h,
                 const __bf16* __restrict__ hb,
                 const int*   __restrict__ src,
                 const int*   __restrict__ dst,
                 const float* __restrict__ enorm,
                 const float* __restrict__ mu,
                 const __bf16* __restrict__ B1,
                 const __bf16* __restrict__ B2,
                 float* __restrict__ out) {
    // Wave-private H tiles: 4 waves x 32 rows x 136 bf16 = 34816 B -> 4 blocks/CU.
    __shared__ __bf16 Hs[4 * WEDGES * LDH2];

    const int tid  = threadIdx.x;
    const int w    = tid >> 6;
    const int lane = tid & 63;
    const int ln   = lane & 15;
    const int q    = lane >> 4;
    const int g0   = blockIdx.x * BEDGES + w * WEDGES;

    // Per-m-tile edge data (rows ln of each 16-row slab; uniform across q).
    int nsrc[2], ndst[2];
    float dval[2];
#pragma unroll
    for (int mt = 0; mt < 2; ++mt) {
        int e = g0 + mt * 16 + ln;
        nsrc[mt] = src[e];
        ndst[mt] = dst[e];
        dval[mt] = enorm[e];
    }

    // ---- Layer 1: [32 x 256pad] @ [256 x 128] ----
    fx4 acc1[2][8];
#pragma unroll
    for (int mt = 0; mt < 2; ++mt)
#pragma unroll
        for (int nt = 0; nt < 8; ++nt)
            acc1[mt][nt] = (fx4){0.f, 0.f, 0.f, 0.f};

    const bf16x8* pB1 = (const bf16x8*)B1;

    // kk = 0..3: gathered node features (src halves then dst halves)
#pragma unroll
    for (int kk = 0; kk < 4; ++kk) {
        const int cb = (kk & 1) * 32 + q * 8;
        bf16x8 a[2];
#pragma unroll
        for (int mt = 0; mt < 2; ++mt) {
            int node = (kk < 2) ? nsrc[mt] : ndst[mt];
            if constexpr (HB16)
                a[mt] = *(const bf16x8*)(hb + (size_t)node * FEAT + cb);
            else
                a[mt] = hfrag_f32(h, node, cb);
        }
#pragma unroll
        for (int nt = 0; nt < 8; ++nt) {
            bf16x8 b = pB1[(kk * 4 + q) * 128 + nt * 16 + ln];
            acc1[0][nt] = __builtin_amdgcn_mfma_f32_16x16x32_bf16(a[0], b, acc1[0][nt], 0, 0, 0);
            acc1[1][nt] = __builtin_amdgcn_mfma_f32_16x16x32_bf16(a[1], b, acc1[1][nt], 0, 0, 0);
        }
    }

    // kk = 4..6: RBF columns c0 = (kk-4)*32 + q*8 .. +7, all < 100
#pragma unroll
    for (int kk = 4; kk < 7; ++kk) {
        const int c0 = (kk - 4) * 32 + q * 8;
        float4 m0 = *(const float4*)(mu + c0);
        float4 m1 = *(const float4*)(mu + c0 + 4);
        bf16x8 a[2];
#pragma unroll
        for (int mt = 0; mt < 2; ++mt) {
            float d = dval[mt];
            float t0 = m0.x - d, t1 = m0.y - d, t2 = m0.z - d, t3 = m0.w - d;
            float t4 = m1.x - d, t5 = m1.y - d, t6 = m1.z - d, t7 = m1.w - d;
            a[mt] = (bf16x8){ (__bf16)__expf(-10.f * t0 * t0), (__bf16)__expf(-10.f * t1 * t1),
                              (__bf16)__expf(-10.f * t2 * t2), (__bf16)__expf(-10.f * t3 * t3),
                              (__bf16)__expf(-10.f * t4 * t4), (__bf16)__expf(-10.f * t5 * t5),
                              (__bf16)__expf(-10.f * t6 * t6), (__bf16)__expf(-10.f * t7 * t7) };
        }
#pragma unroll
        for (int nt = 0; nt < 8; ++nt) {
            bf16x8 b = pB1[(kk * 4 + q) * 128 + nt * 16 + ln];
            acc1[0][nt] = __builtin_amdgcn_mfma_f32_16x16x32_bf16(a[0], b, acc1[0][nt], 0, 0, 0);
            acc1[1][nt] = __builtin_amdgcn_mfma_f32_16x16x32_bf16(a[1], b, acc1[1][nt], 0, 0, 0);
        }
    }

    // kk = 7: only q==0 lanes carry real values (RBF cols 96..99), rest zero.
    {
        float4 m7 = *(const float4*)(mu + 96);
        const __bf16 zz = (__bf16)0.0f;
        const bool qz = (q == 0);
        bf16x8 a[2];
#pragma unroll
        for (int mt = 0; mt < 2; ++mt) {
            float d = dval[mt];
            float t0 = m7.x - d, t1 = m7.y - d, t2 = m7.z - d, t3 = m7.w - d;
            a[mt] = (bf16x8){ qz ? (__bf16)__expf(-10.f * t0 * t0) : zz,
                              qz ? (__bf16)__expf(-10.f * t1 * t1) : zz,
                              qz ? (__bf16)__expf(-10.f * t2 * t2) : zz,
                              qz ? (__bf16)__expf(-10.f * t3 * t3) : zz,
                              zz, zz, zz, zz };
        }
#pragma unroll
        for (int nt = 0; nt < 8; ++nt) {
            bf16x8 b = pB1[(7 * 4 + q) * 128 + nt * 16 + ln];
            acc1[0][nt] = __builtin_amdgcn_mfma_f32_16x16x32_bf16(a[0], b, acc1[0][nt], 0, 0, 0);
            acc1[1][nt] = __builtin_amdgcn_mfma_f32_16x16x32_bf16(a[1], b, acc1[1][nt], 0, 0, 0);
        }
    }

    // ---- SiLU + wave-private transpose (C-layout -> row-major bf16) ----
    // silu(z) = z * sigmoid(z); v_rcp_f32 (~1 ulp) instead of the ~10-op
    // precise-fdiv expansion -- error far below bf16 storage rounding.
    __bf16* Hw = &Hs[w * WEDGES * LDH2];
#pragma unroll
    for (int mt = 0; mt < 2; ++mt)
#pragma unroll
        for (int nt = 0; nt < 8; ++nt)
#pragma unroll
            for (int r = 0; r < 4; ++r) {
                float z = acc1[mt][nt][r];
                float s = z * __builtin_amdgcn_rcpf(1.0f + __expf(-z));
                Hw[(mt * 16 + q * 4 + r) * LDH2 + nt * 16 + ln] = (__bf16)s;
            }
    // Same-wave LDS RAW: compiler inserts lgkmcnt waits; no __syncthreads needed.

    // ---- Layer 2: [32 x 128] @ [128 x 64] ----
    fx4 acc2[2][4];
#pragma unroll
    for (int mt = 0; mt < 2; ++mt)
#pragma unroll
        for (int nt = 0; nt < 4; ++nt)
            acc2[mt][nt] = (fx4){0.f, 0.f, 0.f, 0.f};

    const bf16x8* pB2 = (const bf16x8*)B2;
#pragma unroll
    for (int kk = 0; kk < 4; ++kk) {
        bf16x8 a2[2];
#pragma unroll
        for (int mt = 0; mt < 2; ++mt)
            a2[mt] = *(const bf16x8*)&Hw[(mt * 16 + ln) * LDH2 + kk * 32 + q * 8];
#pragma unroll
        for (int nt = 0; nt < 4; ++nt) {
            bf16x8 b2 = pB2[(kk * 4 + q) * 64 + nt * 16 + ln];
            acc2[0][nt] = __builtin_amdgcn_mfma_f32_16x16x32_bf16(a2[0], b2, acc2[0][nt], 0, 0, 0);
            acc2[1][nt] = __builtin_amdgcn_mfma_f32_16x16x32_bf16(a2[1], b2, acc2[1][nt], 0, 0, 0);
        }
    }

    // ---- Store ----
#pragma unroll
    for (int mt = 0; mt < 2; ++mt)
#pragma unroll
        for (int nt = 0; nt < 4; ++nt)
#pragma unroll
            for (int r = 0; r < 4; ++r)
                out[(size_t)(g0 + mt * 16 + q * 4 + r) * ODIM + nt * 16 + ln] = acc2[mt][nt][r];
}

extern "C" void kernel_launch(void* const* d_in, const int* in_sizes, int n_in,
                              void* d_out, int out_size, void* d_ws, size_t ws_size,
                              hipStream_t stream) {
    const float* h   = (const float*)d_in[0];
    const int*   src = (const int*)d_in[1];
    const int*   dst = (const int*)d_in[2];
    const float* en  = (const float*)d_in[3];
    const float* mu  = (const float*)d_in[4];
    const float* W1  = (const float*)d_in[5];
    const float* W2  = (const float*)d_in[6];

    __bf16* B1 = (__bf16*)d_ws;                          // 32768 bf16 = 64 KB
    __bf16* B2 = (__bf16*)((char*)d_ws + 65536);         // 8192 bf16  = 16 KB
    __bf16* HB = (__bf16*)((char*)d_ws + 81920);         // 3.2M bf16  = 6.4 MB

    const size_t ws_needed = 81920 + (size_t)HN8 * 8 * sizeof(__bf16);
    const bool   use_hb    = ws_size >= ws_needed;

    pack_w<<<160, 256, 0, stream>>>(W1, W2, B1, B2);

    const int E = in_sizes[1];                 // 800000
    const int nblocks = E / BEDGES;            // 6250

    if (use_hb) {
        pack_h<<<(HN8 + 255) / 256, 256, 0, stream>>>(h, HB);
        edges_fused<true><<<nblocks, 256, 0, stream>>>(h, HB, src, dst, en, mu, B1, B2, (float*)d_out);
    } else {
        edges_fused<false><<<nblocks, 256, 0, stream>>>(h, nullptr, src, dst, en, mu, B1, B2, (float*)d_out);
    }
}

// Round 2
// 328.197 us; speedup vs baseline: 1.0887x; 1.0887x over previous
//
#include <hip/hip_runtime.h>
#include <hip/hip_bf16.h>

// Edges GNN message MLP: per-edge RBF(100) + gather h[src],h[dst] (64+64)
// -> Linear(228->128) -> SiLU -> Linear(128->64).
// R5 design: weights resident in LDS. Each wave still owns WEDGES=32 edges
// end-to-end, but blocks are 8 waves (512 threads) and B1/B2 are staged into
// LDS once per block, turning ~80 global weight-fragment loads per wave
// (L1-thrashing, ~200-600cy each -- the R4-measured latency wall) into
// pipelined ds_read_b128. Gathers are issued into registers BEFORE the
// staging barrier so their latency overlaps the one-time stage.
// LDS: 64K (B1) + 16K (B2) + 8*8.7K (Hs) = 148 KB -> 1 block/CU, 2 waves/SIMD.

#define FEAT     64
#define NMU      100
#define K1_REAL  228
#define HID      128
#define ODIM     64
#define K2       128
#define WEDGES   32        // edges per wave
#define NWAVES   8
#define BEDGES   (WEDGES * NWAVES)   // 256 edges per block
#define LDH2     136       // bf16 leading dim of per-wave H tile (16B-aligned rows)
#define HN8      400000    // (50000*64)/8 bf16x8 groups in h

typedef __bf16 bf16x8 __attribute__((ext_vector_type(8)));
typedef float  fx4    __attribute__((ext_vector_type(4)));

// Pack W1 [128 x 228] and W2 [64 x 128] fp32 -> bf16 MFMA B-fragment order.
// B1[((kk*4+q)*128 + n)*8 + j] = W1[n][kk*32 + q*8 + j]  (0 if k >= 228)
// B2[((kk*4+q)*64  + n)*8 + j] = W2[n][kk*32 + q*8 + j]
__global__ void pack_w(const float* __restrict__ W1, const float* __restrict__ W2,
                       __bf16* __restrict__ B1, __bf16* __restrict__ B2) {
    int i = blockIdx.x * 256 + threadIdx.x;     // 0..40959
    if (i < 32768) {
        int j  = i & 7;
        int n  = (i >> 3) & 127;
        int qk = i >> 10;
        int k  = (qk >> 2) * 32 + (qk & 3) * 8 + j;
        float v = (k < K1_REAL) ? W1[n * K1_REAL + k] : 0.0f;
        B1[i] = (__bf16)v;
    } else {
        int t = i - 32768;
        int j  = t & 7;
        int n  = (t >> 3) & 63;
        int qk = t >> 9;
        int k  = (qk >> 2) * 32 + (qk & 3) * 8 + j;
        B2[t] = (__bf16)W2[n * K2 + k];
    }
}

// Convert h [50000 x 64] fp32 -> bf16 table (row-major, same layout).
__global__ void pack_h(const float* __restrict__ h, __bf16* __restrict__ hb) {
    int i = blockIdx.x * 256 + threadIdx.x;     // one bf16x8 group each
    if (i >= HN8) return;
    const float4* p = (const float4*)h + (size_t)i * 2;
    float4 v0 = p[0];
    float4 v1 = p[1];
    bf16x8 b = { (__bf16)v0.x, (__bf16)v0.y, (__bf16)v0.z, (__bf16)v0.w,
                 (__bf16)v1.x, (__bf16)v1.y, (__bf16)v1.z, (__bf16)v1.w };
    ((bf16x8*)hb)[i] = b;
}

__device__ __forceinline__ bf16x8 hfrag_f32(const float* __restrict__ h, int node, int cb) {
    const float4* p = (const float4*)(h + (size_t)node * FEAT + cb);
    float4 v0 = p[0];
    float4 v1 = p[1];
    bf16x8 a = { (__bf16)v0.x, (__bf16)v0.y, (__bf16)v0.z, (__bf16)v0.w,
                 (__bf16)v1.x, (__bf16)v1.y, (__bf16)v1.z, (__bf16)v1.w };
    return a;
}

template<bool HB16>
__global__ __launch_bounds__(512, 2)
void edges_fused(const float* __restrict__ h,
                 const __bf16* __restrict__ hb,
                 const int*   __restrict__ src,
                 const int*   __restrict__ dst,
                 const float* __restrict__ enorm,
                 const float* __restrict__ mu,
                 const __bf16* __restrict__ B1,
                 const __bf16* __restrict__ B2,
                 float* __restrict__ out) {
    // 64K + 16K + 68K = 148 KB static LDS -> 1 block/CU.
    __shared__ __bf16 B1s[32768];
    __shared__ __bf16 B2s[8192];
    __shared__ __bf16 Hs[NWAVES * WEDGES * LDH2];

    const int tid  = threadIdx.x;
    const int w    = tid >> 6;
    const int lane = tid & 63;
    const int ln   = lane & 15;
    const int q    = lane >> 4;
    const int g0   = blockIdx.x * BEDGES + w * WEDGES;

    // ---- Edge data + gathers into registers (before the staging barrier,
    // so gather latency overlaps the weight stage) ----
    int nsrc[2], ndst[2];
    float dval[2];
#pragma unroll
    for (int mt = 0; mt < 2; ++mt) {
        int e = g0 + mt * 16 + ln;
        nsrc[mt] = src[e];
        ndst[mt] = dst[e];
        dval[mt] = enorm[e];
    }

    bf16x8 ag[4][2];     // [kk][mt] gathered A-fragments, 32 VGPRs
#pragma unroll
    for (int kk = 0; kk < 4; ++kk) {
        const int cb = (kk & 1) * 32 + q * 8;
#pragma unroll
        for (int mt = 0; mt < 2; ++mt) {
            int node = (kk < 2) ? nsrc[mt] : ndst[mt];
            if constexpr (HB16)
                ag[kk][mt] = *(const bf16x8*)(hb + (size_t)node * FEAT + cb);
            else
                ag[kk][mt] = hfrag_f32(h, node, cb);
        }
    }

    // ---- Stage weights into LDS (once per block) ----
    {
        const bf16x8* gB1 = (const bf16x8*)B1;
        const bf16x8* gB2 = (const bf16x8*)B2;
        bf16x8* sB1 = (bf16x8*)B1s;
        bf16x8* sB2 = (bf16x8*)B2s;
#pragma unroll
        for (int it = 0; it < 8; ++it) {   // 4096 groups / 512 threads
            int g = it * 512 + tid;
            sB1[g] = gB1[g];
        }
#pragma unroll
        for (int it = 0; it < 2; ++it) {   // 1024 groups / 512 threads
            int g = it * 512 + tid;
            sB2[g] = gB2[g];
        }
    }
    __syncthreads();

    // ---- Layer 1: [32 x 256pad] @ [256 x 128] ----
    fx4 acc1[2][8];
#pragma unroll
    for (int mt = 0; mt < 2; ++mt)
#pragma unroll
        for (int nt = 0; nt < 8; ++nt)
            acc1[mt][nt] = (fx4){0.f, 0.f, 0.f, 0.f};

    // kk = 0..3: gathered node features (already in registers)
#pragma unroll
    for (int kk = 0; kk < 4; ++kk) {
#pragma unroll
        for (int nt = 0; nt < 8; ++nt) {
            bf16x8 b = *(const bf16x8*)&B1s[(((kk * 4 + q) * 128) + nt * 16 + ln) * 8];
            acc1[0][nt] = __builtin_amdgcn_mfma_f32_16x16x32_bf16(ag[kk][0], b, acc1[0][nt], 0, 0, 0);
            acc1[1][nt] = __builtin_amdgcn_mfma_f32_16x16x32_bf16(ag[kk][1], b, acc1[1][nt], 0, 0, 0);
        }
    }

    // kk = 4..6: RBF columns c0 = (kk-4)*32 + q*8 .. +7, all < 100
#pragma unroll
    for (int kk = 4; kk < 7; ++kk) {
        const int c0 = (kk - 4) * 32 + q * 8;
        float4 m0 = *(const float4*)(mu + c0);
        float4 m1 = *(const float4*)(mu + c0 + 4);
        bf16x8 a[2];
#pragma unroll
        for (int mt = 0; mt < 2; ++mt) {
            float d = dval[mt];
            float t0 = m0.x - d, t1 = m0.y - d, t2 = m0.z - d, t3 = m0.w - d;
            float t4 = m1.x - d, t5 = m1.y - d, t6 = m1.z - d, t7 = m1.w - d;
            a[mt] = (bf16x8){ (__bf16)__expf(-10.f * t0 * t0), (__bf16)__expf(-10.f * t1 * t1),
                              (__bf16)__expf(-10.f * t2 * t2), (__bf16)__expf(-10.f * t3 * t3),
                              (__bf16)__expf(-10.f * t4 * t4), (__bf16)__expf(-10.f * t5 * t5),
                              (__bf16)__expf(-10.f * t6 * t6), (__bf16)__expf(-10.f * t7 * t7) };
        }
#pragma unroll
        for (int nt = 0; nt < 8; ++nt) {
            bf16x8 b = *(const bf16x8*)&B1s[(((kk * 4 + q) * 128) + nt * 16 + ln) * 8];
            acc1[0][nt] = __builtin_amdgcn_mfma_f32_16x16x32_bf16(a[0], b, acc1[0][nt], 0, 0, 0);
            acc1[1][nt] = __builtin_amdgcn_mfma_f32_16x16x32_bf16(a[1], b, acc1[1][nt], 0, 0, 0);
        }
    }

    // kk = 7: only q==0 lanes carry real values (RBF cols 96..99), rest zero.
    {
        float4 m7 = *(const float4*)(mu + 96);
        const __bf16 zz = (__bf16)0.0f;
        const bool qz = (q == 0);
        bf16x8 a[2];
#pragma unroll
        for (int mt = 0; mt < 2; ++mt) {
            float d = dval[mt];
            float t0 = m7.x - d, t1 = m7.y - d, t2 = m7.z - d, t3 = m7.w - d;
            a[mt] = (bf16x8){ qz ? (__bf16)__expf(-10.f * t0 * t0) : zz,
                              qz ? (__bf16)__expf(-10.f * t1 * t1) : zz,
                              qz ? (__bf16)__expf(-10.f * t2 * t2) : zz,
                              qz ? (__bf16)__expf(-10.f * t3 * t3) : zz,
                              zz, zz, zz, zz };
        }
#pragma unroll
        for (int nt = 0; nt < 8; ++nt) {
            bf16x8 b = *(const bf16x8*)&B1s[(((7 * 4 + q) * 128) + nt * 16 + ln) * 8];
            acc1[0][nt] = __builtin_amdgcn_mfma_f32_16x16x32_bf16(a[0], b, acc1[0][nt], 0, 0, 0);
            acc1[1][nt] = __builtin_amdgcn_mfma_f32_16x16x32_bf16(a[1], b, acc1[1][nt], 0, 0, 0);
        }
    }

    // ---- SiLU + wave-private transpose (C-layout -> row-major bf16) ----
    // silu(z) = z * sigmoid(z); v_rcp_f32 (~1 ulp) -- error far below bf16
    // storage rounding.
    __bf16* Hw = &Hs[w * WEDGES * LDH2];
#pragma unroll
    for (int mt = 0; mt < 2; ++mt)
#pragma unroll
        for (int nt = 0; nt < 8; ++nt)
#pragma unroll
            for (int r = 0; r < 4; ++r) {
                float z = acc1[mt][nt][r];
                float s = z * __builtin_amdgcn_rcpf(1.0f + __expf(-z));
                Hw[(mt * 16 + q * 4 + r) * LDH2 + nt * 16 + ln] = (__bf16)s;
            }
    // Same-wave LDS RAW: compiler inserts lgkmcnt waits; no __syncthreads needed.

    // ---- Layer 2: [32 x 128] @ [128 x 64] ----
    fx4 acc2[2][4];
#pragma unroll
    for (int mt = 0; mt < 2; ++mt)
#pragma unroll
        for (int nt = 0; nt < 4; ++nt)
            acc2[mt][nt] = (fx4){0.f, 0.f, 0.f, 0.f};

#pragma unroll
    for (int kk = 0; kk < 4; ++kk) {
        bf16x8 a2[2];
#pragma unroll
        for (int mt = 0; mt < 2; ++mt)
            a2[mt] = *(const bf16x8*)&Hw[(mt * 16 + ln) * LDH2 + kk * 32 + q * 8];
#pragma unroll
        for (int nt = 0; nt < 4; ++nt) {
            bf16x8 b2 = *(const bf16x8*)&B2s[(((kk * 4 + q) * 64) + nt * 16 + ln) * 8];
            acc2[0][nt] = __builtin_amdgcn_mfma_f32_16x16x32_bf16(a2[0], b2, acc2[0][nt], 0, 0, 0);
            acc2[1][nt] = __builtin_amdgcn_mfma_f32_16x16x32_bf16(a2[1], b2, acc2[1][nt], 0, 0, 0);
        }
    }

    // ---- Store ----
#pragma unroll
    for (int mt = 0; mt < 2; ++mt)
#pragma unroll
        for (int nt = 0; nt < 4; ++nt)
#pragma unroll
            for (int r = 0; r < 4; ++r)
                out[(size_t)(g0 + mt * 16 + q * 4 + r) * ODIM + nt * 16 + ln] = acc2[mt][nt][r];
}

extern "C" void kernel_launch(void* const* d_in, const int* in_sizes, int n_in,
                              void* d_out, int out_size, void* d_ws, size_t ws_size,
                              hipStream_t stream) {
    const float* h   = (const float*)d_in[0];
    const int*   src = (const int*)d_in[1];
    const int*   dst = (const int*)d_in[2];
    const float* en  = (const float*)d_in[3];
    const float* mu  = (const float*)d_in[4];
    const float* W1  = (const float*)d_in[5];
    const float* W2  = (const float*)d_in[6];

    __bf16* B1 = (__bf16*)d_ws;                          // 32768 bf16 = 64 KB
    __bf16* B2 = (__bf16*)((char*)d_ws + 65536);         // 8192 bf16  = 16 KB
    __bf16* HB = (__bf16*)((char*)d_ws + 81920);         // 3.2M bf16  = 6.4 MB

    const size_t ws_needed = 81920 + (size_t)HN8 * 8 * sizeof(__bf16);
    const bool   use_hb    = ws_size >= ws_needed;

    pack_w<<<160, 256, 0, stream>>>(W1, W2, B1, B2);

    const int E = in_sizes[1];                 // 800000
    const int nblocks = E / BEDGES;            // 3125

    if (use_hb) {
        pack_h<<<(HN8 + 255) / 256, 256, 0, stream>>>(h, HB);
        edges_fused<true><<<nblocks, 512, 0, stream>>>(h, HB, src, dst, en, mu, B1, B2, (float*)d_out);
    } else {
        edges_fused<false><<<nblocks, 512, 0, stream>>>(h, nullptr, src, dst, en, mu, B1, B2, (float*)d_out);
    }
}